// Round 2
// baseline (333.805 us; speedup 1.0000x reference)
//
#include <hip/hip_runtime.h>

#define DEV __device__ __forceinline__

typedef __attribute__((ext_vector_type(8))) short short8;
typedef __attribute__((ext_vector_type(4))) float f32x4;
typedef unsigned short u16;

struct Ptrs { const void* p[32]; };

// ---------------- compile-time problem constants ----------------
constexpr int N_TOK = 65536;
constexpr int cK  [5] = {4,4,5,6,6};              // feats per expert
constexpr int cK1 [5] = {256,256,320,384,384};    // K*D
constexpr int cKT [5] = {8,8,10,12,12};           // K1/32
constexpr int cN2 [5] = {264,264,256,256,256};    // head out cols
constexpr int cNT [5] = {17,17,16,16,16};         // ceil(N2/16)
constexpr int cC0 [5] = {0,264,528,784,1040};     // output col offset
// register sources: 0:A 1:X 2:Y 3:SP 4:P 5:PCH 6:PCL 7:Op 8:Val 9:carry(P&1)
constexpr int cKID[5][6] = {{0,8,9,7,0,0},{0,8,9,7,0,0},{0,1,2,8,7,0},
                            {5,6,4,8,3,7},{0,1,3,4,8,7}};
// bf16 workspace element offsets
constexpr int cEOFF[5] = {0,65536,131072,212992,311296};      // emb, tot 409600
constexpr int cWOFF[5] = {0,131072,262144,425984,622592};     // W1t, tot 819200
constexpr int cHOFF[5] = {0,139264,278528,417792,557056};     // headT, tot 696320
constexpr int EMB_TOT = 409600, W1_TOT = 819200, HEAD_TOT = 696320;
constexpr int PREP_TOT = EMB_TOT + W1_TOT + HEAD_TOT;         // 1,925,120

// ws byte offsets
constexpr size_t WS_COUNTS = 0;
constexpr size_t WS_BUCKET = 256;
constexpr size_t WS_EMB    = 256 + (size_t)5 * N_TOK * 4;
constexpr size_t WS_W1T    = WS_EMB + (size_t)EMB_TOT * 2;
constexpr size_t WS_HT     = WS_W1T + (size_t)W1_TOT * 2;

constexpr int ROWS = 32;        // tokens per tile
constexpr int HP   = 520;       // hbuf pitch (bf16)

struct Smem {
  u16 hbuf[ROWS * HP];          // 33,280 B
  int tokb[ROWS];
  int idsb[ROWS * 6];
};                              // ~34,176 B -> 4 blocks/CU

DEV u16 f2bf(float f) {              // RNE f32 -> bf16 (finite inputs)
  unsigned u = __builtin_bit_cast(unsigned, f);
  u += 0x7FFFu + ((u >> 16) & 1u);
  return (u16)(u >> 16);
}

DEV float gelu_f(float x) {          // tanh-approx gelu (JAX default)
  float u = 0.7978845608028654f * x * (1.0f + 0.044715f * x * x);
  float t2 = fminf(fmaxf(2.0f * u, -30.0f), 30.0f);
  float e = __expf(t2);
  float th = (e - 1.0f) / (e + 1.0f);
  return 0.5f * x * (1.0f + th);
}

// ---------------- prep: f32 -> bf16 (+ transposes, head packing) ----------------
__global__ __launch_bounds__(256) void prep_kernel(Ptrs in, u16* embB, u16* w1tB, u16* hTB) {
  int idx = blockIdx.x * 256 + threadIdx.x;
  if (idx < EMB_TOT) {
    int e = 0, off = idx;
    while (off >= cK[e] * 16384) { off -= cK[e] * 16384; ++e; }
    const float* src = (const float*)in.p[10 + 3*e];
    embB[cEOFF[e] + off] = f2bf(src[off]);
  } else if (idx < EMB_TOT + W1_TOT) {
    int off = idx - EMB_TOT;
    int e = 0;
    while (off >= 512 * cK1[e]) { off -= 512 * cK1[e]; ++e; }
    int K1 = cK1[e];
    int n = off / K1, k = off - n * K1;       // W1t[n][k] = W1[k][n]
    const float* w1 = (const float*)in.p[11 + 3*e];
    w1tB[cWOFF[e] + off] = f2bf(w1[k * 512 + n]);
  } else {
    int off = idx - (EMB_TOT + W1_TOT);
    int e = off / 139264, r = off - e * 139264;
    int n = r >> 9, k = r & 511;              // headT[n][k], n in [0,272)
    float v = 0.0f;
    if (e < 2) {
      if (n < 256)       v = ((const float*)in.p[25 + 2*e])[k * 256 + n];
      else if (n < 264)  v = ((const float*)in.p[26 + 2*e])[k * 8 + (n - 256)];
    } else {
      if (n < 256)       v = ((const float*)in.p[29 + (e - 2)])[k * 256 + n];
    }
    hTB[cHOFF[e] + r] = f2bf(v);
  }
}

// ---------------- bucket tokens by fu ----------------
__global__ __launch_bounds__(256) void bucket_kernel(const int* Op, const int* fu_map,
                                                     int* counts, int* buckets) {
  __shared__ int lc[5], lb[5];
  int tid = threadIdx.x;
  if (tid < 5) lc[tid] = 0;
  __syncthreads();
  int t = blockIdx.x * 256 + tid;
  int fu = fu_map[Op[t]];
  int lp = atomicAdd(&lc[fu], 1);
  __syncthreads();
  if (tid < 5) lb[tid] = atomicAdd(&counts[tid], lc[tid]);
  __syncthreads();
  buckets[fu * N_TOK + lb[fu] + lp] = t;
}

// ---------------- one 32-token tile of one expert ----------------
template<int E>
DEV void expert_tile(const Ptrs& in, int tile, int count, const int* buckets,
                     const u16* embB, const u16* w1tB, const u16* hTB,
                     float* out, Smem& sm) {
  constexpr int K1 = cK1[E], KT = cKT[E], N2 = cN2[E], C0 = cC0[E];
  constexpr int NT = cNT[E], KE = cK[E];

  const int tid = threadIdx.x;
  const int vr = min(count - tile * ROWS, ROWS);
  const int rbase = E * N_TOK + tile * ROWS;

  __syncthreads();   // protect smem reuse across persistent-loop iterations

  if (tid < ROWS)
    sm.tokb[tid] = (tid < vr) ? buckets[rbase + tid] : -1;
  for (int i = tid; i < ROWS * KE; i += 256) {
    int r = i / KE, k = i - r * KE;
    int t = buckets[rbase + ((r < vr) ? r : 0)];
    int s = cKID[E][k];
    int v = (s == 9) ? (((const int*)in.p[4])[t] & 1)
                     : ((const int*)in.p[s])[t];
    sm.idsb[r * 6 + k] = v;
  }
  __syncthreads();

  // zero-fill inactive output columns (single-pass full-row write)
  {
    constexpr int ZC  = (1296 - N2) / 4;
    constexpr int ZLO = C0 / 4;
    constexpr int ZHI = (C0 + N2) / 4;
    int tot = vr * ZC;
    for (int i = tid; i < tot; i += 256) {
      int r = i / ZC, c = i - r * ZC;
      size_t t = (size_t)sm.tokb[r];
      int col4 = (c < ZLO) ? c : (c - ZLO + ZHI);
      *(float4*)(out + t * 1296 + col4 * 4) = make_float4(0.f, 0.f, 0.f, 0.f);
    }
  }

  const int lane = tid & 63, wave = tid >> 6;
  const int l15 = lane & 15, lq = lane >> 4;

  // cache this lane's row ids in registers (static indexing only)
  int myids[2][KE];
  #pragma unroll
  for (int m = 0; m < 2; ++m)
    #pragma unroll
    for (int k = 0; k < KE; ++k)
      myids[m][k] = sm.idsb[(m * 16 + l15) * 6 + k];

  const u16* embE = embB + cEOFF[E];
  const u16* w1e  = w1tB + cWOFF[E];
  const float* b1 = (const float*)in.p[12 + 3 * E];

  // GEMM1: h[32][512] = gelu(f @ W1 + b1); A gathered straight from L2
  #pragma unroll 1
  for (int half = 0; half < 2; ++half) {
    f32x4 acc[2][4];
    const f32x4 z = {0.f, 0.f, 0.f, 0.f};
    #pragma unroll
    for (int m = 0; m < 2; ++m)
      #pragma unroll
      for (int nt = 0; nt < 4; ++nt) acc[m][nt] = z;

    #pragma unroll
    for (int kt = 0; kt < KT; ++kt) {
      constexpr int DUMMY = 0; (void)DUMMY;
      const int kf = kt >> 1;                 // compile-time under unroll
      const int d  = (kt & 1) * 32 + lq * 8;  // 8 elems within one emb row
      short8 a[2];
      #pragma unroll
      for (int m = 0; m < 2; ++m)
        a[m] = *(const short8*)(embE + ((size_t)(kf * 256 + myids[m][kf]) << 6) + d);
      #pragma unroll
      for (int nt = 0; nt < 4; ++nt) {
        int n0 = wave * 128 + half * 64 + nt * 16;
        short8 b = *(const short8*)(w1e + (n0 + l15) * K1 + kt * 32 + lq * 8);
        #pragma unroll
        for (int m = 0; m < 2; ++m)
          acc[m][nt] = __builtin_amdgcn_mfma_f32_16x16x32_bf16(a[m], b, acc[m][nt], 0, 0, 0);
      }
    }
    #pragma unroll
    for (int nt = 0; nt < 4; ++nt) {
      int col = wave * 128 + half * 64 + nt * 16 + l15;
      float b1v = b1[col];
      #pragma unroll
      for (int m = 0; m < 2; ++m)
        #pragma unroll
        for (int r = 0; r < 4; ++r)
          sm.hbuf[(m * 16 + lq * 4 + r) * HP + col] = f2bf(gelu_f(acc[m][nt][r] + b1v));
    }
  }
  __syncthreads();

  // GEMM2: out_tile = h @ headT; wave w takes n-tiles {w, w+4, ...}
  const u16* hTe = hTB + cHOFF[E];
  f32x4 acc2[2][5];
  {
    const f32x4 z = {0.f, 0.f, 0.f, 0.f};
    #pragma unroll
    for (int m = 0; m < 2; ++m)
      #pragma unroll
      for (int j = 0; j < 5; ++j) acc2[m][j] = z;
  }
  #pragma unroll 1
  for (int kt = 0; kt < 16; ++kt) {
    short8 a[2];
    #pragma unroll
    for (int m = 0; m < 2; ++m)
      a[m] = *(const short8*)(sm.hbuf + (m * 16 + l15) * HP + kt * 32 + lq * 8);
    #pragma unroll
    for (int j = 0; j < 5; ++j) {
      int nt = wave + 4 * j;
      if (nt >= NT) break;
      short8 b = *(const short8*)(hTe + (nt * 16 + l15) * 512 + kt * 32 + lq * 8);
      #pragma unroll
      for (int m = 0; m < 2; ++m)
        acc2[m][j] = __builtin_amdgcn_mfma_f32_16x16x32_bf16(a[m], b, acc2[m][j], 0, 0, 0);
    }
  }

  int trow[2][4];
  #pragma unroll
  for (int m = 0; m < 2; ++m)
    #pragma unroll
    for (int r = 0; r < 4; ++r)
      trow[m][r] = sm.tokb[m * 16 + lq * 4 + r];

  #pragma unroll
  for (int j = 0; j < 5; ++j) {
    int nt = wave + 4 * j;
    if (nt >= NT) break;
    int coln = nt * 16 + l15;
    if (coln < N2) {
      #pragma unroll
      for (int m = 0; m < 2; ++m)
        #pragma unroll
        for (int r = 0; r < 4; ++r) {
          int t = trow[m][r];
          if (t >= 0) out[(size_t)t * 1296 + C0 + coln] = acc2[m][j][r];
        }
    }
  }
}

// ---------------- persistent driver ----------------
__global__ __launch_bounds__(256, 4) void moe_kernel(Ptrs in, const int* counts,
                                                     const int* buckets,
                                                     const u16* embB, const u16* w1tB,
                                                     const u16* hTB, float* out) {
  __shared__ Smem sm;
  int c0 = counts[0], c1 = counts[1], c2 = counts[2], c3 = counts[3], c4 = counts[4];
  int t0 = (c0 + ROWS - 1) / ROWS;
  int t1 = (c1 + ROWS - 1) / ROWS;
  int t2 = (c2 + ROWS - 1) / ROWS;
  int t3 = (c3 + ROWS - 1) / ROWS;
  int t4 = (c4 + ROWS - 1) / ROWS;
  int p1 = t0, p2 = p1 + t1, p3 = p2 + t2, p4 = p3 + t3, p5 = p4 + t4;

  for (int w = blockIdx.x; w < p5; w += gridDim.x) {
    int e = 0, base = 0, cnt = c0;
    if (w >= p1) { e = 1; base = p1; cnt = c1; }
    if (w >= p2) { e = 2; base = p2; cnt = c2; }
    if (w >= p3) { e = 3; base = p3; cnt = c3; }
    if (w >= p4) { e = 4; base = p4; cnt = c4; }
    int tile = w - base;
    switch (e) {
      case 0: expert_tile<0>(in, tile, cnt, buckets, embB, w1tB, hTB, out, sm); break;
      case 1: expert_tile<1>(in, tile, cnt, buckets, embB, w1tB, hTB, out, sm); break;
      case 2: expert_tile<2>(in, tile, cnt, buckets, embB, w1tB, hTB, out, sm); break;
      case 3: expert_tile<3>(in, tile, cnt, buckets, embB, w1tB, hTB, out, sm); break;
      case 4: expert_tile<4>(in, tile, cnt, buckets, embB, w1tB, hTB, out, sm); break;
    }
  }
}

extern "C" void kernel_launch(void* const* d_in, const int* in_sizes, int n_in,
                              void* d_out, int out_size, void* d_ws, size_t ws_size,
                              hipStream_t stream) {
  char* ws = (char*)d_ws;
  int* counts  = (int*)(ws + WS_COUNTS);
  int* buckets = (int*)(ws + WS_BUCKET);
  u16* embB    = (u16*)(ws + WS_EMB);
  u16* w1tB    = (u16*)(ws + WS_W1T);
  u16* hTB     = (u16*)(ws + WS_HT);

  Ptrs P;
  for (int i = 0; i < 32; ++i) P.p[i] = d_in[i];

  hipMemsetAsync(counts, 0, 5 * sizeof(int), stream);
  prep_kernel<<<PREP_TOT / 256, 256, 0, stream>>>(P, embB, w1tB, hTB);
  bucket_kernel<<<N_TOK / 256, 256, 0, stream>>>((const int*)d_in[7], (const int*)d_in[9],
                                                 counts, buckets);
  moe_kernel<<<2048, 256, 0, stream>>>(P, counts, buckets, embB, w1tB, hTB,
                                       (float*)d_out);
}

// Round 4
// 282.362 us; speedup vs baseline: 1.1822x; 1.1822x over previous
//
#include <hip/hip_runtime.h>

#define DEV __device__ __forceinline__

typedef __attribute__((ext_vector_type(8))) short short8;
typedef __attribute__((ext_vector_type(4))) float f32x4;
typedef unsigned short u16;

struct Ptrs { const void* p[32]; };

// ---------------- compile-time problem constants ----------------
constexpr int N_TOK = 65536;
constexpr int cK  [5] = {4,4,5,6,6};              // feats per expert
constexpr int cK1 [5] = {256,256,320,384,384};    // K*D
constexpr int cKT [5] = {8,8,10,12,12};           // K1/32
constexpr int cN2 [5] = {264,264,256,256,256};    // head out cols
constexpr int cNT [5] = {17,17,16,16,16};         // ceil(N2/16)
constexpr int cC0 [5] = {0,264,528,784,1040};     // output col offset
// register sources: 0:A 1:X 2:Y 3:SP 4:P 5:PCH 6:PCL 7:Op 8:Val 9:carry(P&1)
constexpr int cKID[5][6] = {{0,8,9,7,0,0},{0,8,9,7,0,0},{0,1,2,8,7,0},
                            {5,6,4,8,3,7},{0,1,3,4,8,7}};
// bf16 workspace element offsets
constexpr int cEOFF[5] = {0,65536,131072,212992,311296};      // emb, tot 409600
constexpr int cWOFF[5] = {0,131072,262144,425984,622592};     // W1t, tot 819200
constexpr int cHOFF[5] = {0,139264,278528,417792,557056};     // headT, tot 696320
constexpr int EMB_TOT = 409600, W1_TOT = 819200, HEAD_TOT = 696320;
constexpr int PREP_TOT = EMB_TOT + W1_TOT + HEAD_TOT;         // 1,925,120

// ws byte offsets
constexpr size_t WS_COUNTS = 0;
constexpr size_t WS_BUCKET = 256;
constexpr size_t WS_EMB    = 256 + (size_t)5 * N_TOK * 4;
constexpr size_t WS_W1T    = WS_EMB + (size_t)EMB_TOT * 2;
constexpr size_t WS_HT     = WS_W1T + (size_t)W1_TOT * 2;

constexpr int ROWS = 64;        // tokens per tile
constexpr int HP   = 520;       // hbuf pitch (bf16)

struct Smem {
  u16 hbuf[ROWS * HP];          // 66,560 B
  int tokb[ROWS];
  int idsb[ROWS * 6];
};                              // ~68,352 B -> 2 blocks/CU

DEV u16 f2bf(float f) {              // RNE f32 -> bf16 (finite inputs)
  unsigned u = __builtin_bit_cast(unsigned, f);
  u += 0x7FFFu + ((u >> 16) & 1u);
  return (u16)(u >> 16);
}

DEV float gelu_f(float x) {          // tanh-approx gelu (JAX default)
  float u = 0.7978845608028654f * x * (1.0f + 0.044715f * x * x);
  float t2 = fminf(fmaxf(2.0f * u, -30.0f), 30.0f);
  float e = __expf(t2);
  float th = (e - 1.0f) / (e + 1.0f);
  return 0.5f * x * (1.0f + th);
}

// ---------------- prep: f32 -> bf16 (+ transposes, head packing) ----------------
__global__ __launch_bounds__(256) void prep_kernel(Ptrs in, u16* embB, u16* w1tB, u16* hTB) {
  int idx = blockIdx.x * 256 + threadIdx.x;
  if (idx < EMB_TOT) {
    int e = 0, off = idx;
    while (off >= cK[e] * 16384) { off -= cK[e] * 16384; ++e; }
    const float* src = (const float*)in.p[10 + 3*e];
    embB[cEOFF[e] + off] = f2bf(src[off]);
  } else if (idx < EMB_TOT + W1_TOT) {
    int off = idx - EMB_TOT;
    int e = 0;
    while (off >= 512 * cK1[e]) { off -= 512 * cK1[e]; ++e; }
    int K1 = cK1[e];
    int n = off / K1, k = off - n * K1;       // W1t[n][k] = W1[k][n]
    const float* w1 = (const float*)in.p[11 + 3*e];
    w1tB[cWOFF[e] + off] = f2bf(w1[k * 512 + n]);
  } else {
    int off = idx - (EMB_TOT + W1_TOT);
    int e = off / 139264, r = off - e * 139264;
    int n = r >> 9, k = r & 511;              // headT[n][k], n in [0,272)
    float v = 0.0f;
    if (e < 2) {
      if (n < 256)       v = ((const float*)in.p[25 + 2*e])[k * 256 + n];
      else if (n < 264)  v = ((const float*)in.p[26 + 2*e])[k * 8 + (n - 256)];
    } else {
      if (n < 256)       v = ((const float*)in.p[29 + (e - 2)])[k * 256 + n];
    }
    hTB[cHOFF[e] + r] = f2bf(v);
  }
}

// ---------------- bucket tokens by fu ----------------
__global__ __launch_bounds__(256) void bucket_kernel(const int* Op, const int* fu_map,
                                                     int* counts, int* buckets) {
  __shared__ int lc[5], lb[5];
  int tid = threadIdx.x;
  if (tid < 5) lc[tid] = 0;
  __syncthreads();
  int t = blockIdx.x * 256 + tid;
  int fu = fu_map[Op[t]];
  int lp = atomicAdd(&lc[fu], 1);
  __syncthreads();
  if (tid < 5) lb[tid] = atomicAdd(&counts[tid], lc[tid]);
  __syncthreads();
  buckets[fu * N_TOK + lb[fu] + lp] = t;
}

// ---------------- one 64-token tile of one expert ----------------
template<int E>
DEV void expert_tile(const Ptrs& in, int tile, int count, const int* buckets,
                     const u16* embB, const u16* w1tB, const u16* hTB,
                     float* out, Smem& sm) {
  constexpr int K1 = cK1[E], KT = cKT[E], N2 = cN2[E], C0 = cC0[E];
  constexpr int NT = cNT[E], KE = cK[E];

  const int tid = threadIdx.x;
  const int vr = min(count - tile * ROWS, ROWS);
  const int rbase = E * N_TOK + tile * ROWS;

  __syncthreads();   // protect smem reuse across persistent-loop iterations

  if (tid < ROWS)
    sm.tokb[tid] = (tid < vr) ? buckets[rbase + tid] : -1;
  for (int i = tid; i < ROWS * KE; i += 256) {
    int r = i / KE, k = i - r * KE;
    int t = buckets[rbase + ((r < vr) ? r : 0)];
    int s = cKID[E][k];
    int v = (s == 9) ? (((const int*)in.p[4])[t] & 1)
                     : ((const int*)in.p[s])[t];
    sm.idsb[r * 6 + k] = v;
  }
  __syncthreads();

  const int lane = tid & 63, wave = tid >> 6;
  const int l15 = lane & 15, lq = lane >> 4;

  // zero-fill inactive output columns, non-temporal (single-pass full-row write)
  {
    constexpr int ZC  = (1296 - N2) / 4;   // float4s of zeros per row
    constexpr int ZLO = C0 / 4;
    constexpr int ZHI = (C0 + N2) / 4;
    const f32x4 z4 = {0.f, 0.f, 0.f, 0.f};
    for (int r = wave; r < vr; r += 4) {
      float* rowp = out + (size_t)sm.tokb[r] * 1296;
      #pragma unroll
      for (int c = 0; c < ZC; c += 64) {
        int cc = c + lane;
        if (cc < ZC) {
          int col4 = (cc < ZLO) ? cc : (cc - ZLO + ZHI);
          __builtin_nontemporal_store(z4, (f32x4*)(rowp + col4 * 4));
        }
      }
    }
  }

  // cache this lane's row ids in registers (static indexing only)
  int myids[4][KE];
  #pragma unroll
  for (int m = 0; m < 4; ++m)
    #pragma unroll
    for (int k = 0; k < KE; ++k)
      myids[m][k] = sm.idsb[(m * 16 + l15) * 6 + k];

  const u16* embE = embB + cEOFF[E];
  const u16* w1e  = w1tB + cWOFF[E];
  const float* b1 = (const float*)in.p[12 + 3 * E];

  // GEMM1: h[64][512] = gelu(f @ W1 + b1); A gathered straight from L2
  #pragma unroll 1
  for (int half = 0; half < 2; ++half) {
    f32x4 acc[4][4];
    const f32x4 z = {0.f, 0.f, 0.f, 0.f};
    #pragma unroll
    for (int m = 0; m < 4; ++m)
      #pragma unroll
      for (int nt = 0; nt < 4; ++nt) acc[m][nt] = z;

    #pragma unroll
    for (int kt = 0; kt < KT; ++kt) {
      const int kf = kt >> 1;                 // compile-time under unroll
      const int d  = (kt & 1) * 32 + lq * 8;  // 8 elems within one emb row
      short8 a[4];
      #pragma unroll
      for (int m = 0; m < 4; ++m)
        a[m] = *(const short8*)(embE + ((size_t)(kf * 256 + myids[m][kf]) << 6) + d);
      #pragma unroll
      for (int nt = 0; nt < 4; ++nt) {
        int n0 = wave * 128 + half * 64 + nt * 16;
        short8 b = *(const short8*)(w1e + (n0 + l15) * K1 + kt * 32 + lq * 8);
        #pragma unroll
        for (int m = 0; m < 4; ++m)
          acc[m][nt] = __builtin_amdgcn_mfma_f32_16x16x32_bf16(a[m], b, acc[m][nt], 0, 0, 0);
      }
    }
    #pragma unroll
    for (int nt = 0; nt < 4; ++nt) {
      int col = wave * 128 + half * 64 + nt * 16 + l15;
      float b1v = b1[col];
      #pragma unroll
      for (int m = 0; m < 4; ++m)
        #pragma unroll
        for (int r = 0; r < 4; ++r)
          sm.hbuf[(m * 16 + lq * 4 + r) * HP + col] = f2bf(gelu_f(acc[m][nt][r] + b1v));
    }
  }
  __syncthreads();

  // GEMM2: out_tile = h @ headT; wave w takes n-tiles {w, w+4, ...}
  const u16* hTe = hTB + cHOFF[E];
  f32x4 acc2[4][5];
  {
    const f32x4 z = {0.f, 0.f, 0.f, 0.f};
    #pragma unroll
    for (int m = 0; m < 4; ++m)
      #pragma unroll
      for (int j = 0; j < 5; ++j) acc2[m][j] = z;
  }
  #pragma unroll 4
  for (int kt = 0; kt < 16; ++kt) {
    short8 a[4];
    #pragma unroll
    for (int m = 0; m < 4; ++m)
      a[m] = *(const short8*)(sm.hbuf + (m * 16 + l15) * HP + kt * 32 + lq * 8);
    #pragma unroll
    for (int j = 0; j < 5; ++j) {
      int nt = wave + 4 * j;
      if (nt >= NT) break;
      short8 b = *(const short8*)(hTe + (nt * 16 + l15) * 512 + kt * 32 + lq * 8);
      #pragma unroll
      for (int m = 0; m < 4; ++m)
        acc2[m][j] = __builtin_amdgcn_mfma_f32_16x16x32_bf16(a[m], b, acc2[m][j], 0, 0, 0);
    }
  }

  int trow[4][4];
  #pragma unroll
  for (int m = 0; m < 4; ++m)
    #pragma unroll
    for (int r = 0; r < 4; ++r)
      trow[m][r] = sm.tokb[m * 16 + lq * 4 + r];

  #pragma unroll
  for (int j = 0; j < 5; ++j) {
    int nt = wave + 4 * j;
    if (nt >= NT) break;
    int coln = nt * 16 + l15;
    if (coln < N2) {
      #pragma unroll
      for (int m = 0; m < 4; ++m)
        #pragma unroll
        for (int r = 0; r < 4; ++r) {
          int t = trow[m][r];
          if (t >= 0)
            __builtin_nontemporal_store(acc2[m][j][r],
                                        out + (size_t)t * 1296 + C0 + coln);
        }
    }
  }
}

// ---------------- persistent driver with expert->XCD affinity ----------------
__global__ __launch_bounds__(256, 2) void moe_kernel(Ptrs in, const int* counts,
                                                     const int* buckets,
                                                     const u16* embB, const u16* w1tB,
                                                     const u16* hTB, float* out) {
  __shared__ Smem sm;
  int c0 = counts[0], c1 = counts[1], c2 = counts[2], c3 = counts[3], c4 = counts[4];
  int t0 = (c0 + ROWS - 1) / ROWS;
  int t1 = (c1 + ROWS - 1) / ROWS;
  int t2 = (c2 + ROWS - 1) / ROWS;
  int t3 = (c3 + ROWS - 1) / ROWS;
  int t4 = (c4 + ROWS - 1) / ROWS;
  int p1 = t0, p2 = p1 + t1, p3 = p2 + t2, p4 = p3 + t3, p5 = p4 + t4;

  // tiles are expert-major [0, p5); XCD x owns the contiguous slice
  // [x*p5/8, (x+1)*p5/8) so each XCD's L2 sees <= 2 experts' weights.
  const int x = blockIdx.x & 7;        // XCD (dispatch heuristic bid%8)
  const int slot = blockIdx.x >> 3;    // 0..63
  const int beg = (x * p5) >> 3;
  const int end = ((x + 1) * p5) >> 3;

  for (int g = beg + slot; g < end; g += 64) {
    int e = 0, base = 0, cnt = c0;
    if (g >= p1) { e = 1; base = p1; cnt = c1; }
    if (g >= p2) { e = 2; base = p2; cnt = c2; }
    if (g >= p3) { e = 3; base = p3; cnt = c3; }
    if (g >= p4) { e = 4; base = p4; cnt = c4; }
    int tile = g - base;
    switch (e) {
      case 0: expert_tile<0>(in, tile, cnt, buckets, embB, w1tB, hTB, out, sm); break;
      case 1: expert_tile<1>(in, tile, cnt, buckets, embB, w1tB, hTB, out, sm); break;
      case 2: expert_tile<2>(in, tile, cnt, buckets, embB, w1tB, hTB, out, sm); break;
      case 3: expert_tile<3>(in, tile, cnt, buckets, embB, w1tB, hTB, out, sm); break;
      case 4: expert_tile<4>(in, tile, cnt, buckets, embB, w1tB, hTB, out, sm); break;
    }
  }
}

extern "C" void kernel_launch(void* const* d_in, const int* in_sizes, int n_in,
                              void* d_out, int out_size, void* d_ws, size_t ws_size,
                              hipStream_t stream) {
  char* ws = (char*)d_ws;
  int* counts  = (int*)(ws + WS_COUNTS);
  int* buckets = (int*)(ws + WS_BUCKET);
  u16* embB    = (u16*)(ws + WS_EMB);
  u16* w1tB    = (u16*)(ws + WS_W1T);
  u16* hTB     = (u16*)(ws + WS_HT);

  Ptrs P;
  for (int i = 0; i < 32; ++i) P.p[i] = d_in[i];

  (void)hipMemsetAsync(counts, 0, 5 * sizeof(int), stream);
  prep_kernel<<<PREP_TOT / 256, 256, 0, stream>>>(P, embB, w1tB, hTB);
  bucket_kernel<<<N_TOK / 256, 256, 0, stream>>>((const int*)d_in[7], (const int*)d_in[9],
                                                 counts, buckets);
  moe_kernel<<<512, 256, 0, stream>>>(P, counts, buckets, embB, w1tB, hTB,
                                      (float*)d_out);
}

// Round 5
// 236.536 us; speedup vs baseline: 1.4112x; 1.1937x over previous
//
#include <hip/hip_runtime.h>

#define DEV __device__ __forceinline__

typedef __attribute__((ext_vector_type(8))) short short8;
typedef __attribute__((ext_vector_type(4))) float f32x4;
typedef unsigned short u16;

struct Ptrs { const void* p[32]; };

// ---------------- compile-time problem constants ----------------
constexpr int N_TOK = 65536;
constexpr int cK  [5] = {4,4,5,6,6};              // feats per expert
constexpr int cK1 [5] = {256,256,320,384,384};    // K*D
constexpr int cN2 [5] = {264,264,256,256,256};    // head out cols
constexpr int cNT [5] = {17,17,16,16,16};         // ceil(N2/16)
constexpr int cC0 [5] = {0,264,528,784,1040};     // output col offset
// register sources: 0:A 1:X 2:Y 3:SP 4:P 5:PCH 6:PCL 7:Op 8:Val 9:carry(P&1)
constexpr int cKID[5][6] = {{0,8,9,7,0,0},{0,8,9,7,0,0},{0,1,2,8,7,0},
                            {5,6,4,8,3,7},{0,1,3,4,8,7}};
// bf16 workspace element offsets
constexpr int cEOFF[5] = {0,65536,131072,212992,311296};      // emb, tot 409600
constexpr int cWOFF[5] = {0,131072,262144,425984,622592};     // W1t, tot 819200
constexpr int cHOFF[5] = {0,139264,278528,417792,557056};     // headT, tot 696320
constexpr int EMB_TOT = 409600, W1_TOT = 819200, HEAD_TOT = 696320;
constexpr int PREP_TOT = EMB_TOT + W1_TOT + HEAD_TOT;         // 1,925,120

// ws byte offsets
constexpr size_t WS_COUNTS = 0;
constexpr size_t WS_BUCKET = 256;
constexpr size_t WS_EMB    = 256 + (size_t)5 * N_TOK * 4;
constexpr size_t WS_W1T    = WS_EMB + (size_t)EMB_TOT * 2;
constexpr size_t WS_HT     = WS_W1T + (size_t)W1_TOT * 2;

constexpr int ROWS = 128;       // tokens per tile
constexpr int HP   = 520;       // hbuf pitch (bf16 elems), 1040B stride -> 2-way (free)

// LDS layout (dynamic): [0,98304) fbuf (aliased) / [0,133120) hbuf / tokb / idsb
constexpr int TOK_OFF = ROWS * HP * 2;            // 133,120
constexpr int IDS_OFF = TOK_OFF + ROWS * 4;       // 133,632
constexpr int LDS_BYTES = IDS_OFF + ROWS * 6 * 4; // 136,704

DEV u16 f2bf(float f) {              // RNE f32 -> bf16 (finite inputs)
  unsigned u = __builtin_bit_cast(unsigned, f);
  u += 0x7FFFu + ((u >> 16) & 1u);
  return (u16)(u >> 16);
}

DEV float gelu_f(float x) {          // tanh-approx gelu (JAX default)
  float u = 0.7978845608028654f * x * (1.0f + 0.044715f * x * x);
  float t2 = fminf(fmaxf(2.0f * u, -30.0f), 30.0f);
  float e = __expf(t2);
  float th = (e - 1.0f) / (e + 1.0f);
  return 0.5f * x * (1.0f + th);
}

// ---------------- prep: f32 -> bf16 (+ transposes, head packing) ----------------
__global__ __launch_bounds__(256) void prep_kernel(Ptrs in, u16* embB, u16* w1tB, u16* hTB) {
  int idx = blockIdx.x * 256 + threadIdx.x;
  if (idx < EMB_TOT) {
    int e = 0, off = idx;
    while (off >= cK[e] * 16384) { off -= cK[e] * 16384; ++e; }
    const float* src = (const float*)in.p[10 + 3*e];
    embB[cEOFF[e] + off] = f2bf(src[off]);
  } else if (idx < EMB_TOT + W1_TOT) {
    int off = idx - EMB_TOT;
    int e = 0;
    while (off >= 512 * cK1[e]) { off -= 512 * cK1[e]; ++e; }
    int K1 = cK1[e];
    int n = off / K1, k = off - n * K1;       // W1t[n][k] = W1[k][n]
    const float* w1 = (const float*)in.p[11 + 3*e];
    w1tB[cWOFF[e] + off] = f2bf(w1[k * 512 + n]);
  } else {
    int off = idx - (EMB_TOT + W1_TOT);
    int e = off / 139264, r = off - e * 139264;
    int n = r >> 9, k = r & 511;              // headT[n][k], n in [0,272)
    float v = 0.0f;
    if (e < 2) {
      if (n < 256)       v = ((const float*)in.p[25 + 2*e])[k * 256 + n];
      else if (n < 264)  v = ((const float*)in.p[26 + 2*e])[k * 8 + (n - 256)];
    } else {
      if (n < 256)       v = ((const float*)in.p[29 + (e - 2)])[k * 256 + n];
    }
    hTB[cHOFF[e] + r] = f2bf(v);
  }
}

// ---------------- bucket tokens by fu ----------------
__global__ __launch_bounds__(256) void bucket_kernel(const int* Op, const int* fu_map,
                                                     int* counts, int* buckets) {
  __shared__ int lc[5], lb[5];
  int tid = threadIdx.x;
  if (tid < 5) lc[tid] = 0;
  __syncthreads();
  int t = blockIdx.x * 256 + tid;
  int fu = fu_map[Op[t]];
  int lp = atomicAdd(&lc[fu], 1);
  __syncthreads();
  if (tid < 5) lb[tid] = atomicAdd(&counts[tid], lc[tid]);
  __syncthreads();
  buckets[fu * N_TOK + lb[fu] + lp] = t;
}

// ---------------- one 128-token tile of one expert (512 threads) ----------------
template<int E>
DEV void expert_tile(const Ptrs& in, int tile, int count, const int* buckets,
                     const u16* embB, const u16* w1tB, const u16* hTB,
                     float* out, char* smem) {
  constexpr int K1 = cK1[E], KT = cK1[E] / 32, N2 = cN2[E], C0 = cC0[E];
  constexpr int NT = cNT[E], KE = cK[E];
  constexpr int FB  = K1 * 2;        // fbuf row stride, bytes
  constexpr int CPR = KE * 8;        // 16B chunks per fbuf row

  u16* hbuf = (u16*)smem;
  int* tokb = (int*)(smem + TOK_OFF);
  int* idsb = (int*)(smem + IDS_OFF);

  const int tid = threadIdx.x;
  const int vr = min(count - tile * ROWS, ROWS);
  const int rbase = E * N_TOK + tile * ROWS;

  __syncthreads();   // prior iteration's LDS reads complete before overwrite

  if (tid < ROWS)
    tokb[tid] = (tid < vr) ? buckets[rbase + tid] : -1;
  for (int i = tid; i < ROWS * KE; i += 512) {
    int r = i / KE, k = i - r * KE;
    int t = buckets[rbase + ((r < vr) ? r : 0)];
    int s = cKID[E][k];
    int v = (s == 9) ? (((const int*)in.p[4])[t] & 1)
                     : ((const int*)in.p[s])[t];
    idsb[r * 6 + k] = v;
  }
  __syncthreads();

  const int lane = tid & 63, wave = tid >> 6;
  const int l15 = lane & 15, lq = (lane >> 4) & 3;

  // zero-fill inactive output columns, non-temporal
  {
    constexpr int ZC  = (1296 - N2) / 4;   // f32x4 zeros per row
    constexpr int ZLO = C0 / 4;
    constexpr int ZHI = (C0 + N2) / 4;
    const f32x4 z4 = {0.f, 0.f, 0.f, 0.f};
    for (int r = wave; r < vr; r += 8) {
      float* rowp = out + (size_t)tokb[r] * 1296;
      #pragma unroll
      for (int c = 0; c < ZC; c += 64) {
        int cc = c + lane;
        if (cc < ZC) {
          int col4 = (cc < ZLO) ? cc : (cc - ZLO + ZHI);
          __builtin_nontemporal_store(z4, (f32x4*)(rowp + col4 * 4));
        }
      }
    }
  }

  // gather A into LDS (XOR-swizzled rows), reg-staged; KT chunks per thread
  {
    const u16* embE = embB + cEOFF[E];
    short8 val[KT];
    int    dst[KT];
    #pragma unroll
    for (int it = 0; it < KT; ++it) {
      int d = tid + it * 512;            // chunk id, total 16*K1 = 512*KT
      int r = d / CPR, c = d - r * CPR;  // row, chunk-in-row
      int k = c >> 3;
      int id = idsb[r * 6 + k];
      val[it] = *(const short8*)(embE + (size_t)((k * 256 + id) << 6) + ((c & 7) << 3));
      dst[it] = r * FB + ((c * 16) ^ ((r & 7) << 4));
    }
    #pragma unroll
    for (int it = 0; it < KT; ++it)
      *(short8*)(smem + dst[it]) = val[it];
  }
  __syncthreads();

  const u16* w1e  = w1tB + cWOFF[E];
  const float* b1 = (const float*)in.p[12 + 3 * E];

  // GEMM1: each wave owns 64 cols (wave*64 .. +64); all 128 rows
  f32x4 acc[8][4];
  {
    const f32x4 z = {0.f, 0.f, 0.f, 0.f};
    #pragma unroll
    for (int m = 0; m < 8; ++m)
      #pragma unroll
      for (int nt = 0; nt < 4; ++nt) acc[m][nt] = z;
  }
  #pragma unroll 2
  for (int kt = 0; kt < KT; ++kt) {
    short8 a[8], b[4];
    #pragma unroll
    for (int m = 0; m < 8; ++m) {
      int row = m * 16 + l15;
      a[m] = *(const short8*)(smem + row * FB + ((kt * 64 + lq * 16) ^ ((row & 7) << 4)));
    }
    #pragma unroll
    for (int nt = 0; nt < 4; ++nt)
      b[nt] = *(const short8*)(w1e + (wave * 64 + nt * 16 + l15) * K1 + kt * 32 + lq * 8);
    #pragma unroll
    for (int nt = 0; nt < 4; ++nt)
      #pragma unroll
      for (int m = 0; m < 8; ++m)
        acc[m][nt] = __builtin_amdgcn_mfma_f32_16x16x32_bf16(a[m], b[nt], acc[m][nt], 0, 0, 0);
  }
  __syncthreads();   // all fbuf reads done before h overwrites the region

  #pragma unroll
  for (int nt = 0; nt < 4; ++nt) {
    int col = wave * 64 + nt * 16 + l15;
    float b1v = b1[col];
    #pragma unroll
    for (int m = 0; m < 8; ++m)
      #pragma unroll
      for (int q = 0; q < 4; ++q)
        hbuf[(m * 16 + lq * 4 + q) * HP + col] = f2bf(gelu_f(acc[m][nt][q] + b1v));
  }
  __syncthreads();

  // GEMM2: wave w takes head n-tiles {w, w+8, (w+16)}
  const u16* hTe = hTB + cHOFF[E];
  f32x4 acc2[8][3];
  {
    const f32x4 z = {0.f, 0.f, 0.f, 0.f};
    #pragma unroll
    for (int m = 0; m < 8; ++m)
      #pragma unroll
      for (int j = 0; j < 3; ++j) acc2[m][j] = z;
  }
  #pragma unroll 4
  for (int kt = 0; kt < 16; ++kt) {
    short8 a[8];
    #pragma unroll
    for (int m = 0; m < 8; ++m)
      a[m] = *(const short8*)(hbuf + (m * 16 + l15) * HP + kt * 32 + lq * 8);
    #pragma unroll
    for (int j = 0; j < 3; ++j) {
      int nt = wave + 8 * j;
      if (nt >= NT) break;
      short8 b = *(const short8*)(hTe + (nt * 16 + l15) * 512 + kt * 32 + lq * 8);
      #pragma unroll
      for (int m = 0; m < 8; ++m)
        acc2[m][j] = __builtin_amdgcn_mfma_f32_16x16x32_bf16(a[m], b, acc2[m][j], 0, 0, 0);
    }
  }

  int trow[8][4];
  #pragma unroll
  for (int m = 0; m < 8; ++m)
    #pragma unroll
    for (int q = 0; q < 4; ++q)
      trow[m][q] = tokb[m * 16 + lq * 4 + q];

  #pragma unroll
  for (int j = 0; j < 3; ++j) {
    int nt = wave + 8 * j;
    if (nt >= NT) break;
    int coln = nt * 16 + l15;
    if (coln < N2) {
      #pragma unroll
      for (int m = 0; m < 8; ++m)
        #pragma unroll
        for (int q = 0; q < 4; ++q) {
          int t = trow[m][q];
          if (t >= 0)
            __builtin_nontemporal_store(acc2[m][j][q],
                                        out + (size_t)t * 1296 + C0 + coln);
        }
    }
  }
}

// ---------------- persistent driver with expert->XCD affinity ----------------
__global__ __launch_bounds__(512, 2) void moe_kernel(Ptrs in, const int* counts,
                                                     const int* buckets,
                                                     const u16* embB, const u16* w1tB,
                                                     const u16* hTB, float* out) {
  extern __shared__ char smem[];
  int c0 = counts[0], c1 = counts[1], c2 = counts[2], c3 = counts[3], c4 = counts[4];
  int t0 = (c0 + ROWS - 1) / ROWS;
  int t1 = (c1 + ROWS - 1) / ROWS;
  int t2 = (c2 + ROWS - 1) / ROWS;
  int t3 = (c3 + ROWS - 1) / ROWS;
  int t4 = (c4 + ROWS - 1) / ROWS;
  int p1 = t0, p2 = p1 + t1, p3 = p2 + t2, p4 = p3 + t3, p5 = p4 + t4;

  // tiles are expert-major [0, p5); XCD x owns a contiguous slice.
  const int x = blockIdx.x & 7;        // XCD (dispatch heuristic bid%8)
  const int slot = blockIdx.x >> 3;    // 0..63
  const int beg = (x * p5) >> 3;
  const int end = ((x + 1) * p5) >> 3;

  for (int g = beg + slot; g < end; g += 64) {
    int e = 0, base = 0, cnt = c0;
    if (g >= p1) { e = 1; base = p1; cnt = c1; }
    if (g >= p2) { e = 2; base = p2; cnt = c2; }
    if (g >= p3) { e = 3; base = p3; cnt = c3; }
    if (g >= p4) { e = 4; base = p4; cnt = c4; }
    int tile = g - base;
    switch (e) {
      case 0: expert_tile<0>(in, tile, cnt, buckets, embB, w1tB, hTB, out, smem); break;
      case 1: expert_tile<1>(in, tile, cnt, buckets, embB, w1tB, hTB, out, smem); break;
      case 2: expert_tile<2>(in, tile, cnt, buckets, embB, w1tB, hTB, out, smem); break;
      case 3: expert_tile<3>(in, tile, cnt, buckets, embB, w1tB, hTB, out, smem); break;
      case 4: expert_tile<4>(in, tile, cnt, buckets, embB, w1tB, hTB, out, smem); break;
    }
  }
}

extern "C" void kernel_launch(void* const* d_in, const int* in_sizes, int n_in,
                              void* d_out, int out_size, void* d_ws, size_t ws_size,
                              hipStream_t stream) {
  char* ws = (char*)d_ws;
  int* counts  = (int*)(ws + WS_COUNTS);
  int* buckets = (int*)(ws + WS_BUCKET);
  u16* embB    = (u16*)(ws + WS_EMB);
  u16* w1tB    = (u16*)(ws + WS_W1T);
  u16* hTB     = (u16*)(ws + WS_HT);

  Ptrs P;
  for (int i = 0; i < 32; ++i) P.p[i] = d_in[i];

  (void)hipMemsetAsync(counts, 0, 5 * sizeof(int), stream);
  prep_kernel<<<PREP_TOT / 256, 256, 0, stream>>>(P, embB, w1tB, hTB);
  bucket_kernel<<<N_TOK / 256, 256, 0, stream>>>((const int*)d_in[7], (const int*)d_in[9],
                                                 counts, buckets);
  moe_kernel<<<512, 512, LDS_BYTES, stream>>>(P, counts, buckets, embB, w1tB, hTB,
                                              (float*)d_out);
}